// Round 1
// baseline (285.585 us; speedup 1.0000x reference)
//
#include <hip/hip_runtime.h>
#include <cstdint>

typedef __attribute__((ext_vector_type(8))) short short8;     // 8 bf16 (4 VGPRs)
typedef __attribute__((ext_vector_type(4))) float floatx4;    // MFMA C/D frag
typedef __attribute__((ext_vector_type(4))) unsigned int uintx4;

#define PAD 20   // words per (row,col) cell: 16 kpair-words + 4 pad (keeps b128 16B-aligned, odd/4 for bank spread)

__device__ __forceinline__ uint32_t pack2_bf16(float a, float b) {
    uint32_t ua = __builtin_bit_cast(uint32_t, a);
    uint32_t ub = __builtin_bit_cast(uint32_t, b);
    ua = (ua + 0x7FFFu + ((ua >> 16) & 1u)) >> 16;   // RNE
    ub = (ub + 0x7FFFu + ((ub >> 16) & 1u)) >> 16;
    return ua | (ub << 16);                           // lo = even channel, hi = odd channel
}

__device__ __forceinline__ short8 frag_ld(const uint32_t* p) {
    uintx4 v = *(const uintx4*)p;                     // ds_read_b128
    return __builtin_bit_cast(short8, v);
}

// out[b, di*9+dj, h, w] = sum_c f1[b,c,h,w] * f2[b,c,h+di-4,w+dj-4]  (zero-padded)
// Banded A^T*B via mfma 16x16x32 bf16. Block = 4 waves = 4 h rows; wave tile M=32 w.
__global__ __launch_bounds__(256, 2)
void corr_kernel(const float* __restrict__ f1, const float* __restrict__ f2,
                 float* __restrict__ out) {
    // B: 12 rows (h0-4 .. h0+7) x 48 cols (w0-4 .. w0+43) x 16 kpairs
    __shared__ uint32_t ldsB[12 * 48 * PAD];   // 46080 B
    // A: 4 h x 32 m x 16 kpairs
    __shared__ uint32_t ldsA[4 * 32 * PAD];    // 10240 B

    const int tid  = threadIdx.x;
    const int lane = tid & 63;
    const int wh   = tid >> 6;        // wave id == h sub-row (0..3)
    const int n15  = lane & 15;
    const int q    = lane >> 4;       // quad

    const int bid = blockIdx.x;
    const int wt = bid & 3;           // w tile (0..3) -> w0 = 32*wt
    const int ht = (bid >> 2) & 15;   // h tile (0..15) -> h0 = 4*ht
    const int b  = bid >> 6;          // batch (0..7)

    const int w0 = wt * 32;
    const int h0 = ht * 4;
    const int h  = h0 + wh;

    // staging decomposition: thread = (kp, cq)
    const int kp = tid & 15;
    const int cq = tid >> 4;          // 0..15

    const float* f1b = f1 + (size_t)(b * 256 + 2 * kp) * 8192;
    const float* f2b = f2 + (size_t)(b * 256 + 2 * kp) * 8192;

    floatx4 acc[9][4];
#pragma unroll
    for (int di = 0; di < 9; ++di)
#pragma unroll
        for (int t = 0; t < 4; ++t)
            acc[di][t] = (floatx4){0.f, 0.f, 0.f, 0.f};

    for (int ch = 0; ch < 8; ++ch) {
        const int coff = ch * 32 * 8192;   // channel-chunk offset (c0 = 32*ch)

        // ---- stage A: f1[b, c0..c0+31, h0+wv, w0+m] -> bf16x2 words
#pragma unroll
        for (int wv = 0; wv < 4; ++wv) {
#pragma unroll
            for (int j = 0; j < 2; ++j) {
                int m = cq + 16 * j;
                const float* p = f1b + coff + (h0 + wv) * 128 + (w0 + m);
                float v0 = p[0];
                float v1 = p[8192];
                ldsA[(wv * 32 + m) * PAD + kp] = pack2_bf16(v0, v1);
            }
        }

        // ---- stage B: f2[b, c0..c0+31, h0-4+r, w0-4+col], zero-fill OOB
#pragma unroll
        for (int r = 0; r < 12; ++r) {
#pragma unroll
            for (int j = 0; j < 3; ++j) {
                int col = cq + 16 * j;
                int gh = h0 - 4 + r;
                int gw = w0 - 4 + col;
                float v0 = 0.f, v1 = 0.f;
                if (((unsigned)gh < 64u) && ((unsigned)gw < 128u)) {
                    const float* p = f2b + coff + gh * 128 + gw;
                    v0 = p[0];
                    v1 = p[8192];
                }
                ldsB[(r * 48 + col) * PAD + kp] = pack2_bf16(v0, v1);
            }
        }
        __syncthreads();

        // ---- compute: A-frag lane: A[m=lane&15][k=quad*8+j]; B-frag: B[k][n=lane&15]
        const uint32_t* pa = &ldsA[(wh * 32 + n15) * PAD + 4 * q];
        short8 a0 = frag_ld(pa);                 // m = 0..15
        short8 a1 = frag_ld(pa + 16 * PAD);      // m = 16..31
#pragma unroll
        for (int di = 0; di < 9; ++di) {
            const uint32_t* pb = &ldsB[((wh + di) * 48 + n15) * PAD + 4 * q];
            short8 b0 = frag_ld(pb);             // cols 0..15   (w0-4 .. w0+11)
            short8 b1 = frag_ld(pb + 16 * PAD);  // cols 16..31
            short8 b2 = frag_ld(pb + 32 * PAD);  // cols 32..47
            acc[di][0] = __builtin_amdgcn_mfma_f32_16x16x32_bf16(a0, b0, acc[di][0], 0, 0, 0);
            acc[di][1] = __builtin_amdgcn_mfma_f32_16x16x32_bf16(a0, b1, acc[di][1], 0, 0, 0);
            acc[di][2] = __builtin_amdgcn_mfma_f32_16x16x32_bf16(a1, b1, acc[di][2], 0, 0, 0);
            acc[di][3] = __builtin_amdgcn_mfma_f32_16x16x32_bf16(a1, b2, acc[di][3], 0, 0, 0);
        }
        __syncthreads();
    }

    // ---- epilogue: band extraction.
    // C/D layout: D[m'= q*4+reg][n'=lane&15]. Tile t: (At,Bt). Global w = w0+At*16+m'.
    // LDS col of that output's dj: At*16+m'+dj = Bt*16+n'  =>  dj = (Bt-At)*16 + n' - m'.
    const int At[4] = {0, 0, 1, 1};
    const int Bt[4] = {0, 1, 1, 2};
#pragma unroll
    for (int di = 0; di < 9; ++di) {
#pragma unroll
        for (int t = 0; t < 4; ++t) {
#pragma unroll
            for (int r = 0; r < 4; ++r) {
                int mp = 4 * q + r;
                int dj = (Bt[t] - At[t]) * 16 + n15 - mp;
                if (dj >= 0 && dj <= 8) {
                    int w = w0 + At[t] * 16 + mp;
                    size_t idx = (((size_t)b * 81 + (size_t)(di * 9 + dj)) * 64 + h) * 128 + w;
                    out[idx] = acc[di][t][r];
                }
            }
        }
    }
}

extern "C" void kernel_launch(void* const* d_in, const int* in_sizes, int n_in,
                              void* d_out, int out_size, void* d_ws, size_t ws_size,
                              hipStream_t stream) {
    const float* f1 = (const float*)d_in[0];
    const float* f2 = (const float*)d_in[1];
    float* out = (float*)d_out;
    // grid: 8 batches x 16 h-tiles x 4 w-tiles
    corr_kernel<<<dim3(512), dim3(256), 0, stream>>>(f1, f2, out);
}

// Round 2
// 197.666 us; speedup vs baseline: 1.4448x; 1.4448x over previous
//
#include <hip/hip_runtime.h>
#include <cstdint>

typedef __attribute__((ext_vector_type(8))) short short8;     // 8 bf16 (4 VGPRs)
typedef __attribute__((ext_vector_type(4))) float floatx4;    // MFMA C/D frag + vec4 load
typedef __attribute__((ext_vector_type(4))) unsigned int uintx4;

#define PAD 20   // words per (row,col) cell: 16 kpair-words + 4 pad (16B-aligned b128 reads)

__device__ __forceinline__ uint32_t pack2_bf16(float a, float b) {
    uint32_t ua = __builtin_bit_cast(uint32_t, a);
    uint32_t ub = __builtin_bit_cast(uint32_t, b);
    ua = (ua + 0x7FFFu + ((ua >> 16) & 1u)) >> 16;   // RNE
    ub = (ub + 0x7FFFu + ((ub >> 16) & 1u)) >> 16;
    return ua | (ub << 16);                           // lo = even channel, hi = odd channel
}

__device__ __forceinline__ short8 frag_ld(const uint32_t* p) {
    uintx4 v = *(const uintx4*)p;                     // ds_read_b128
    return __builtin_bit_cast(short8, v);
}

// out[b, di*9+dj, h, w] = sum_c f1[b,c,h,w] * f2[b,c,h+di-4,w+dj-4]  (zero-padded)
// Banded A^T*B via mfma 16x16x32 bf16. Block = 4 waves = 4 h rows; wave tile M=32 w.
__global__ __launch_bounds__(256, 2)
void corr_kernel(const float* __restrict__ f1, const float* __restrict__ f2,
                 float* __restrict__ out) {
    // B: 12 rows (h0-4 .. h0+7) x 48 cols (w0-4 .. w0+43) x 16 kpairs
    __shared__ uint32_t ldsB[12 * 48 * PAD];   // 46080 B
    // A: 4 h x 32 m x 16 kpairs
    __shared__ uint32_t ldsA[4 * 32 * PAD];    // 10240 B

    const int tid  = threadIdx.x;
    const int lane = tid & 63;
    const int wh   = tid >> 6;        // wave id == h sub-row (0..3)
    const int n15  = lane & 15;
    const int q    = lane >> 4;       // quad

    const int bid = blockIdx.x;
    const int wt = bid & 3;           // w tile (0..3) -> w0 = 32*wt
    const int ht = (bid >> 2) & 15;   // h tile (0..15) -> h0 = 4*ht
    const int b  = bid >> 6;          // batch (0..7)

    const int w0 = wt * 32;
    const int h0 = ht * 4;
    const int h  = h0 + wh;

    floatx4 acc[9][4];
#pragma unroll
    for (int di = 0; di < 9; ++di)
#pragma unroll
        for (int t = 0; t < 4; ++t)
            acc[di][t] = (floatx4){0.f, 0.f, 0.f, 0.f};

    const float* f1b = f1 + (size_t)b * 256 * 8192;
    const float* f2b = f2 + (size_t)b * 256 * 8192;

    for (int ch = 0; ch < 8; ++ch) {
        const int c0 = ch * 32;       // channel chunk base (16 kpairs)

        // ---- stage A: f1[b, c0+2kp(+1), h0+row, w0+4*w4 .. +3] -> 4 packed words
        // task t = tid + 256*s: w4 = t&7 (lane-fastest: coalesced 128B segs),
        // kp = (t>>3)&15 (bank spread), row = t>>7.
#pragma unroll
        for (int s = 0; s < 2; ++s) {
            int t   = tid + 256 * s;
            int w4  = t & 7;
            int kp  = (t >> 3) & 15;
            int row = t >> 7;
            const float* p = f1b + (size_t)(c0 + 2 * kp) * 8192 + (h0 + row) * 128 + (w0 + 4 * w4);
            floatx4 v0 = *(const floatx4*)p;          // channel c0+2kp
            floatx4 v1 = *(const floatx4*)(p + 8192); // channel c0+2kp+1
            uint32_t* dst = &ldsA[(row * 32 + 4 * w4) * PAD + kp];
            dst[0 * PAD] = pack2_bf16(v0.x, v1.x);
            dst[1 * PAD] = pack2_bf16(v0.y, v1.y);
            dst[2 * PAD] = pack2_bf16(v0.z, v1.z);
            dst[3 * PAD] = pack2_bf16(v0.w, v1.w);
        }

        // ---- stage B: f2 tile 12 rows x 48 cols, zero-filled OOB.
        // Every vec4 is fully in-bounds or fully OOB (gw ≡ 0 mod 4, bounds ≡ 0 mod 4).
        // task t: w4 = t%12 (lane-fastest: 192B segs), kp = (t/12)&15, row = (t/12)>>4.
#pragma unroll
        for (int s = 0; s < 9; ++s) {
            int t    = tid + 256 * s;
            int w4   = t % 12;
            int rest = t / 12;
            int kp   = rest & 15;
            int row  = rest >> 4;
            int gh = h0 - 4 + row;
            int gw = w0 - 4 + 4 * w4;
            floatx4 v0 = (floatx4){0.f, 0.f, 0.f, 0.f};
            floatx4 v1 = (floatx4){0.f, 0.f, 0.f, 0.f};
            if (((unsigned)gh < 64u) && ((unsigned)gw < 128u)) {
                const float* p = f2b + (size_t)(c0 + 2 * kp) * 8192 + gh * 128 + gw;
                v0 = *(const floatx4*)p;
                v1 = *(const floatx4*)(p + 8192);
            }
            uint32_t* dst = &ldsB[(row * 48 + 4 * w4) * PAD + kp];
            dst[0 * PAD] = pack2_bf16(v0.x, v1.x);
            dst[1 * PAD] = pack2_bf16(v0.y, v1.y);
            dst[2 * PAD] = pack2_bf16(v0.z, v1.z);
            dst[3 * PAD] = pack2_bf16(v0.w, v1.w);
        }
        __syncthreads();

        // ---- compute: A-frag lane: A[m=lane&15][k=quad*8+j]; B-frag: B[k][n=lane&15]
        const uint32_t* pa = &ldsA[(wh * 32 + n15) * PAD + 4 * q];
        short8 a0 = frag_ld(pa);                 // m = 0..15
        short8 a1 = frag_ld(pa + 16 * PAD);      // m = 16..31
#pragma unroll
        for (int di = 0; di < 9; ++di) {
            const uint32_t* pb = &ldsB[((wh + di) * 48 + n15) * PAD + 4 * q];
            short8 b0 = frag_ld(pb);             // cols 0..15   (w0-4 .. w0+11)
            short8 b1 = frag_ld(pb + 16 * PAD);  // cols 16..31
            short8 b2 = frag_ld(pb + 32 * PAD);  // cols 32..47
            acc[di][0] = __builtin_amdgcn_mfma_f32_16x16x32_bf16(a0, b0, acc[di][0], 0, 0, 0);
            acc[di][1] = __builtin_amdgcn_mfma_f32_16x16x32_bf16(a0, b1, acc[di][1], 0, 0, 0);
            acc[di][2] = __builtin_amdgcn_mfma_f32_16x16x32_bf16(a1, b1, acc[di][2], 0, 0, 0);
            acc[di][3] = __builtin_amdgcn_mfma_f32_16x16x32_bf16(a1, b2, acc[di][3], 0, 0, 0);
        }
        __syncthreads();
    }

    // ---- epilogue: band extraction.
    // C/D layout: D[m'= q*4+reg][n'=lane&15]. Tile t: (At,Bt). Global w = w0+At*16+m'.
    // LDS col of that output's dj: At*16+m'+dj = Bt*16+n'  =>  dj = (Bt-At)*16 + n' - m'.
    const int At[4] = {0, 0, 1, 1};
    const int Bt[4] = {0, 1, 1, 2};
#pragma unroll
    for (int di = 0; di < 9; ++di) {
#pragma unroll
        for (int t = 0; t < 4; ++t) {
#pragma unroll
            for (int r = 0; r < 4; ++r) {
                int mp = 4 * q + r;
                int dj = (Bt[t] - At[t]) * 16 + n15 - mp;
                if (dj >= 0 && dj <= 8) {
                    int w = w0 + At[t] * 16 + mp;
                    size_t idx = (((size_t)b * 81 + (size_t)(di * 9 + dj)) * 64 + h) * 128 + w;
                    out[idx] = acc[di][t][r];
                }
            }
        }
    }
}

extern "C" void kernel_launch(void* const* d_in, const int* in_sizes, int n_in,
                              void* d_out, int out_size, void* d_ws, size_t ws_size,
                              hipStream_t stream) {
    const float* f1 = (const float*)d_in[0];
    const float* f2 = (const float*)d_in[1];
    float* out = (float*)d_out;
    // grid: 8 batches x 16 h-tiles x 4 w-tiles
    corr_kernel<<<dim3(512), dim3(256), 0, stream>>>(f1, f2, out);
}

// Round 4
// 186.080 us; speedup vs baseline: 1.5347x; 1.0623x over previous
//
#include <hip/hip_runtime.h>
#include <cstdint>

typedef __attribute__((ext_vector_type(8))) short short8;     // 8 bf16 (4 VGPRs)
typedef __attribute__((ext_vector_type(4))) float floatx4;
typedef __attribute__((ext_vector_type(2))) unsigned int uintx2;
typedef __attribute__((ext_vector_type(4))) unsigned int uintx4;

#define CS 18                 // LDS cell stride in words (16 kpair + 2 pad): 4*CS mod 32 = 8 -> bank spread
#define A_WORDS (8 * 32 * CS)    // 4608 words
#define B_WORDS (16 * 48 * CS)   // 13824 words

__device__ __forceinline__ uint32_t pack2(float a, float b) {
    uint32_t ua = __builtin_bit_cast(uint32_t, a);
    uint32_t ub = __builtin_bit_cast(uint32_t, b);
    ua = (ua + 0x7FFFu + ((ua >> 16) & 1u)) >> 16;   // RNE (verified R1/R2, absmax 0.5)
    ub = (ub + 0x7FFFu + ((ub >> 16) & 1u)) >> 16;
    return ua | (ub << 16);                           // lo = even channel, hi = odd channel
}

__device__ __forceinline__ short8 frag_ld(const uint32_t* p) {
    uintx2 lo = *(const uintx2*)p;        // ds_read_b64 (cells are 8B-aligned: CS*4=72 ≡ 0 mod 8)
    uintx2 hi = *(const uintx2*)(p + 2);
    uintx4 v = {lo.x, lo.y, hi.x, hi.y};
    return __builtin_bit_cast(short8, v);
}

// out[b, di*9+dj, h, w] = sum_c f1[b,c,h,w] * f2[b,c,h+di-4,w+dj-4]  (zero-padded)
// Banded A^T*B via mfma 16x16x32 bf16. Block = 8 waves = 8 h rows; wave M=32 w, all 81 offsets.
// Double-buffered LDS, register prefetch of next chunk, 1 barrier/chunk.
__global__ __launch_bounds__(512, 2)
void corr_kernel(const float* __restrict__ f1, const float* __restrict__ f2,
                 float* __restrict__ out) {
    __shared__ uint32_t ldsA[2 * A_WORDS];   // 8 rows x 32 w x 16 kpair (+pad)  -> 36 KB
    __shared__ uint32_t ldsB[2 * B_WORDS];   // 16 rows x 48 cols x 16 kpair     -> 108 KB

    const int tid  = threadIdx.x;
    const int lane = tid & 63;
    const int wh   = tid >> 6;        // wave id == h sub-row (0..7)
    const int n15  = lane & 15;
    const int q    = lane >> 4;

    const int bid = blockIdx.x;
    const int b  = bid & 7;           // batch in low bits: XCD (bid%8) partitioned by batch -> L2 locality
    const int ht = (bid >> 3) & 7;    // h tile (0..7) -> h0 = 8*ht
    const int wt = bid >> 6;          // w tile (0..3) -> w0 = 32*wt

    const int w0 = wt * 32;
    const int h0 = ht * 8;
    const int h  = h0 + wh;

    const float* f1b = f1 + (size_t)b * 256 * 8192;
    const float* f2b = f2 + (size_t)b * 256 * 8192;

    // ---- precompute staging tasks (chunk-invariant LDS offsets, chunk-0 pointers)
    // A: 1024 cells-groups: t -> w4=t&7, kp=(t>>3)&15, row=t>>7
    const float* aPtr[2];
    int aOff[2];
#pragma unroll
    for (int s = 0; s < 2; ++s) {
        int t = tid + 512 * s;
        int w4 = t & 7, kp = (t >> 3) & 15, row = t >> 7;
        aPtr[s] = f1b + (size_t)(2 * kp) * 8192 + (h0 + row) * 128 + (w0 + 4 * w4);
        aOff[s] = (row * 32 + 4 * w4) * CS + kp;
    }
    // B: 3072 groups: t -> w4=t%12, kp=(t/12)&15, row=(t/12)>>4; rows h0-4..h0+11, cols w0-4..w0+43
    const float* bPtr[6];
    int bOff[6];
    uint32_t bMask[6];
#pragma unroll
    for (int s = 0; s < 6; ++s) {
        int t = tid + 512 * s;
        int w4 = t % 12;
        int r2 = t / 12;
        int kp = r2 & 15, row = r2 >> 4;
        int gh = h0 - 4 + row;
        int gw = w0 - 4 + 4 * w4;
        bool inb = ((unsigned)gh < 64u) && ((unsigned)gw < 128u);  // vec4 fully in or fully out
        bPtr[s]  = inb ? (f2b + (size_t)(2 * kp) * 8192 + gh * 128 + gw) : f2b;
        bOff[s]  = (row * 48 + 4 * w4) * CS + kp;
        bMask[s] = inb ? 0xFFFFFFFFu : 0u;
    }

    floatx4 acc[9][4];
#pragma unroll
    for (int di = 0; di < 9; ++di)
#pragma unroll
        for (int t = 0; t < 4; ++t)
            acc[di][t] = (floatx4){0.f, 0.f, 0.f, 0.f};

    floatx4 rA[2][2], rB[6][2];
    uint32_t pkA[8], pkB[24];

    auto issue = [&]() {   // non-blocking global loads for the next chunk
#pragma unroll
        for (int s = 0; s < 2; ++s) {
            rA[s][0] = *(const floatx4*)aPtr[s];
            rA[s][1] = *(const floatx4*)(aPtr[s] + 8192);
            aPtr[s] += 32 * 8192;
        }
#pragma unroll
        for (int s = 0; s < 6; ++s) {
            rB[s][0] = *(const floatx4*)bPtr[s];
            rB[s][1] = *(const floatx4*)(bPtr[s] + 8192);
            bPtr[s] += 32 * 8192;
        }
    };
    auto packall = [&]() {
#pragma unroll
        for (int s = 0; s < 2; ++s)
#pragma unroll
            for (int i = 0; i < 4; ++i)
                pkA[4 * s + i] = pack2(rA[s][0][i], rA[s][1][i]);
#pragma unroll
        for (int s = 0; s < 6; ++s)
#pragma unroll
            for (int i = 0; i < 4; ++i)
                pkB[4 * s + i] = pack2(rB[s][0][i], rB[s][1][i]) & bMask[s];
    };

    issue();      // chunk 0
    packall();

    for (int ch = 0; ch < 8; ++ch) {
        uint32_t* bufA = ldsA + (ch & 1) * A_WORDS;
        uint32_t* bufB = ldsB + (ch & 1) * B_WORDS;

        // write current chunk's packed words (conflict-light: banks = 8*w4 + 18*i + kp)
#pragma unroll
        for (int s = 0; s < 2; ++s)
#pragma unroll
            for (int i = 0; i < 4; ++i)
                bufA[aOff[s] + i * CS] = pkA[4 * s + i];
#pragma unroll
        for (int s = 0; s < 6; ++s)
#pragma unroll
            for (int i = 0; i < 4; ++i)
                bufB[bOff[s] + i * CS] = pkB[4 * s + i];

        if (ch < 7) issue();          // next chunk's loads in flight across barrier + compute
        __syncthreads();              // buf[ch&1] complete for all threads

        const uint32_t* pa = bufA + (wh * 32 + n15) * CS + 4 * q;
        short8 a0 = frag_ld(pa);                  // m = 0..15
        short8 a1 = frag_ld(pa + 16 * CS);        // m = 16..31
#pragma unroll
        for (int di = 0; di < 9; ++di) {
            const uint32_t* pb = bufB + ((wh + di) * 48 + n15) * CS + 4 * q;
            short8 b0 = frag_ld(pb);              // cols 0..15  (w0-4 .. w0+11)
            short8 b1 = frag_ld(pb + 16 * CS);    // cols 16..31
            short8 b2 = frag_ld(pb + 32 * CS);    // cols 32..47
            acc[di][0] = __builtin_amdgcn_mfma_f32_16x16x32_bf16(a0, b0, acc[di][0], 0, 0, 0);
            acc[di][1] = __builtin_amdgcn_mfma_f32_16x16x32_bf16(a0, b1, acc[di][1], 0, 0, 0);
            acc[di][2] = __builtin_amdgcn_mfma_f32_16x16x32_bf16(a1, b1, acc[di][2], 0, 0, 0);
            acc[di][3] = __builtin_amdgcn_mfma_f32_16x16x32_bf16(a1, b2, acc[di][3], 0, 0, 0);
        }
        if (ch < 7) packall();        // consume in-flight loads after compute
        // no second barrier: next iteration writes the OTHER buffer; reuse of this
        // buffer only happens at ch+2, which is ordered after the ch+1 barrier.
    }

    // ---- epilogue: band extraction (verified R1/R2).
    // D[m'=q*4+r][n'=lane&15]; dj = (Bt-At)*16 + n' - m'; w = w0 + At*16 + m'.
    const int At[4] = {0, 0, 1, 1};
    const int Bt[4] = {0, 1, 1, 2};
#pragma unroll
    for (int di = 0; di < 9; ++di) {
#pragma unroll
        for (int t = 0; t < 4; ++t) {
#pragma unroll
            for (int r = 0; r < 4; ++r) {
                int mp = 4 * q + r;
                int dj = (Bt[t] - At[t]) * 16 + n15 - mp;
                if (dj >= 0 && dj <= 8) {
                    int w = w0 + At[t] * 16 + mp;
                    size_t idx = (((size_t)b * 81 + (size_t)(di * 9 + dj)) * 64 + h) * 128 + w;
                    out[idx] = acc[di][t][r];
                }
            }
        }
    }
}

extern "C" void kernel_launch(void* const* d_in, const int* in_sizes, int n_in,
                              void* d_out, int out_size, void* d_ws, size_t ws_size,
                              hipStream_t stream) {
    const float* f1 = (const float*)d_in[0];
    const float* f2 = (const float*)d_in[1];
    float* out = (float*)d_out;
    // grid: 8 batches (low bits -> XCD partition) x 8 h-tiles x 4 w-tiles = 256 = 1 block/CU
    corr_kernel<<<dim3(256), dim3(512), 0, stream>>>(f1, f2, out);
}